// Round 3
// baseline (490.297 us; speedup 1.0000x reference)
//
#include <hip/hip_runtime.h>

typedef unsigned short u16;
typedef __attribute__((ext_vector_type(8))) __bf16 bf16x8;
typedef __attribute__((ext_vector_type(4))) float f32x4;

// ---------- bf16 split helpers ----------
static __device__ __forceinline__ u16 f2bf(float f) {
  union { float f; unsigned u; } v; v.f = f;
  unsigned r = v.u + 0x7FFFu + ((v.u >> 16) & 1u);   // RNE
  return (u16)(r >> 16);
}
static __device__ __forceinline__ float bf2f(u16 h) {
  union { unsigned u; float f; } v; v.u = ((unsigned)h) << 16;
  return v.f;
}
static __device__ __forceinline__ f32x4 mfma16(bf16x8 a, bf16x8 b, f32x4 c) {
  return __builtin_amdgcn_mfma_f32_16x16x32_bf16(a, b, c, 0, 0, 0);
}
// async global->LDS, 16B per lane; lds dest is wave-uniform base + lane*16
static __device__ __forceinline__ void gl_lds16(const char* g, char* l) {
  __builtin_amdgcn_global_load_lds(
      (const __attribute__((address_space(1))) unsigned int*)g,
      (__attribute__((address_space(3))) unsigned int*)l, 16, 0, 0);
}

// ============================================================
// Kernel 1: W^T hi/lo split into staging-ready swizzled layout.
// Per matrix: [colhalf 2][khalf 2][row 128][512B row: hi|lo at 16B slots,
// slot' = (slot + 2*row) & 31, lo at slot+16]. 64KB contiguous slabs in
// order s = (mat*2+colhalf)*2+khalf.
// ============================================================
__global__ __launch_bounds__(256) void prep_w_kernel(
    const float* __restrict__ Wq, const float* __restrict__ Wk,
    const float* __restrict__ Wv, u16* __restrict__ wout) {
  int idx = blockIdx.x * 256 + threadIdx.x;   // 0..196607
  int mm = idx >> 16;
  int o  = idx & 65535;
  int row = o >> 8, e = o & 255;
  const float* W = (mm == 0) ? Wq : ((mm == 1) ? Wk : Wv);
  float v = W[e * 256 + row];
  u16 hi = f2bf(v);
  u16 lo = f2bf(v - bf2f(hi));
  int ch = row >> 7, rl = row & 127;
  int kh2 = e >> 7, el = e & 127;
  int slot = el >> 3;
  int sh  = (slot + 2 * rl) & 31;
  int sl2 = (slot + 16 + 2 * rl) & 31;
  size_t b0 = (size_t)mm * 262144 + (size_t)ch * 131072 + (size_t)kh2 * 65536
            + rl * 512 + (el & 7) * 2;
  *(u16*)((char*)wout + b0 + sh * 16) = hi;
  *(u16*)((char*)wout + b0 + sl2 * 16) = lo;
}

// ============================================================
// Kernel 2: fused QKV projection. Grid 256 blocks x 512 thr.
// Block owns 256 tokens; wave owns 32 (A-frags hi/lo in VGPRs, x read ONCE).
// Weights: 12 x 64KB slabs streamed L2->LDS, double-buffered global_load_lds.
// Q,K: 3-term split bf16. V: 1-term (bf16-storage-dominated anyway).
// ============================================================
template<int MAT, int CH, int KHF, bool LAST>
static __device__ __forceinline__ void do_slab(
    char* wlds, const u16* __restrict__ wspl,
    const bf16x8 (&xh8)[2][8], const bf16x8 (&xl8)[2][8],
    f32x4 (&acc)[2][8],
    int w, int l, int l15, int l4, int tok0,
    const float* __restrict__ bq, const float* __restrict__ bk,
    const float* __restrict__ bv,
    u16* __restrict__ qh, u16* __restrict__ ql,
    u16* __restrict__ kh, u16* __restrict__ kl, u16* __restrict__ vt) {
  constexpr int S = (MAT * 2 + CH) * 2 + KHF;
  const char* cbuf = wlds + (S & 1) * 65536;
  if (!LAST) {
    const char* wsrc = (const char*)wspl + (size_t)(S + 1) * 65536;
    char* dbuf = wlds + ((S + 1) & 1) * 65536;
    #pragma unroll
    for (int i = 0; i < 8; i++)
      gl_lds16(wsrc + i * 8192 + w * 1024 + l * 16, dbuf + i * 8192 + w * 1024);
  }
  if (KHF == 0) {
    #pragma unroll
    for (int a = 0; a < 2; a++)
      #pragma unroll
      for (int c = 0; c < 8; c++) acc[a][c] = (f32x4){0.f, 0.f, 0.f, 0.f};
  }
  #pragma unroll
  for (int kk = 0; kk < 4; kk++) {
    #pragma unroll
    for (int ct = 0; ct < 8; ct++) {
      int r = ct * 16 + l15;
      int sbase = kk * 4 + l4;
      int offh = r * 512 + (((sbase + 2 * r) & 31) << 4);
      bf16x8 bh = *(const bf16x8*)(cbuf + offh);
      if (MAT < 2) {
        int offl = r * 512 + (((sbase + 16 + 2 * r) & 31) << 4);
        bf16x8 bl = *(const bf16x8*)(cbuf + offl);
        #pragma unroll
        for (int tt = 0; tt < 2; tt++) {
          bf16x8 ah = xh8[tt][KHF * 4 + kk];
          bf16x8 al = xl8[tt][KHF * 4 + kk];
          acc[tt][ct] = mfma16(ah, bh, acc[tt][ct]);
          acc[tt][ct] = mfma16(al, bh, acc[tt][ct]);
          acc[tt][ct] = mfma16(ah, bl, acc[tt][ct]);
        }
      } else {
        #pragma unroll
        for (int tt = 0; tt < 2; tt++)
          acc[tt][ct] = mfma16(bh, xh8[tt][KHF * 4 + kk], acc[tt][ct]);
      }
    }
  }
  if (KHF == 1) {
    if (MAT < 2) {
      const float* bias = MAT ? bk : bq;
      u16* oh = MAT ? kh : qh;
      u16* ol = MAT ? kl : ql;
      #pragma unroll
      for (int ct = 0; ct < 8; ct++) {
        int col = CH * 128 + ct * 16 + l15;
        float bb = bias[col];
        #pragma unroll
        for (int tt = 0; tt < 2; tt++) {
          #pragma unroll
          for (int j = 0; j < 4; j++) {
            size_t tok = (size_t)(tok0 + tt * 16 + l4 * 4 + j);
            float v = acc[tt][ct][j] + bb;
            u16 hi = f2bf(v);
            u16 lo = f2bf(v - bf2f(hi));
            size_t ci;
            if (MAT == 0) ci = col;
            else ci = (size_t)((((col >> 3) + 2 * (int)tok) & 31) << 3) | (col & 7);
            oh[tok * 256 + ci] = hi;
            ol[tok * 256 + ci] = lo;
          }
        }
      }
    } else {
      #pragma unroll
      for (int ct = 0; ct < 8; ct++) {
        #pragma unroll
        for (int tt = 0; tt < 2; tt++) {
          int t = tok0 + tt * 16 + l15;
          int b2 = t >> 10, tile = (t >> 5) & 31, trel = t & 31;
          size_t tbase = ((size_t)(b2 * 32 + tile)) * 16384;
          #pragma unroll
          for (int j = 0; j < 4; j++) {
            int d = CH * 128 + ct * 16 + l4 * 4 + j;
            float v = acc[tt][ct][j] + bv[d];
            size_t off = tbase
                + ((((d << 6) + ((trel >> 3) << 4)) ^ ((d & 7) << 4)) + ((trel & 7) << 1));
            *(u16*)((char*)vt + off) = f2bf(v);
          }
        }
      }
    }
  }
  __syncthreads();
}

__global__ __launch_bounds__(512, 2) void proj_kernel(
    const float* __restrict__ x, const float* __restrict__ bq,
    const float* __restrict__ bk, const float* __restrict__ bv,
    const u16* __restrict__ wspl,
    u16* __restrict__ qh, u16* __restrict__ ql,
    u16* __restrict__ kh, u16* __restrict__ kl,
    u16* __restrict__ vt) {
  __shared__ __align__(16) char wlds[131072];   // 2 x 64KB slab double-buffer
  const int tid = threadIdx.x;
  const int l = tid & 63, w = tid >> 6;
  const int l15 = l & 15, l4 = l >> 4;
  const int tok0 = blockIdx.x * 256 + w * 32;

  // ---- stage slab 0 while loading x frags ----
  #pragma unroll
  for (int i = 0; i < 8; i++)
    gl_lds16((const char*)wspl + i * 8192 + w * 1024 + l * 16,
             wlds + i * 8192 + w * 1024);

  // ---- x -> hi/lo A-frags in registers (read once) ----
  bf16x8 xh8[2][8], xl8[2][8];
  #pragma unroll
  for (int tt = 0; tt < 2; tt++) {
    const float* xp = x + (size_t)(tok0 + tt * 16 + l15) * 256;
    #pragma unroll
    for (int kq = 0; kq < 8; kq++) {
      const float* p = xp + kq * 32 + l4 * 8;
      float4 f0 = *(const float4*)p;
      float4 f1 = *(const float4*)(p + 4);
      float ff[8] = {f0.x, f0.y, f0.z, f0.w, f1.x, f1.y, f1.z, f1.w};
      union { u16 s[8]; bf16x8 v; } H, L;
      #pragma unroll
      for (int e = 0; e < 8; e++) {
        u16 h = f2bf(ff[e]);
        H.s[e] = h;
        L.s[e] = f2bf(ff[e] - bf2f(h));
      }
      xh8[tt][kq] = H.v;
      xl8[tt][kq] = L.v;
    }
  }
  __syncthreads();   // slab 0 ready

  f32x4 acc[2][8];
  #define ARGS wlds, wspl, xh8, xl8, acc, w, l, l15, l4, tok0, bq, bk, bv, qh, ql, kh, kl, vt
  do_slab<0,0,0,false>(ARGS); do_slab<0,0,1,false>(ARGS);
  do_slab<0,1,0,false>(ARGS); do_slab<0,1,1,false>(ARGS);
  do_slab<1,0,0,false>(ARGS); do_slab<1,0,1,false>(ARGS);
  do_slab<1,1,0,false>(ARGS); do_slab<1,1,1,false>(ARGS);
  do_slab<2,0,0,false>(ARGS); do_slab<2,0,1,false>(ARGS);
  do_slab<2,1,0,false>(ARGS); do_slab<2,1,1,true >(ARGS);
  #undef ARGS
}

// ============================================================
// Kernel 3: flash attention. Grid 512 x 512 thr; block = 128 q rows.
// KVBLK=32; K hi/lo + V tiles double-buffered via global_load_lds
// (prefetch next tile before compute). Defer-max (THR=8) skips
// max-reduce + O-rescale on non-growing tiles. 3-term split scores.
// ============================================================
__global__ __launch_bounds__(512, 2) void attn_kernel(
    const u16* __restrict__ qh_g, const u16* __restrict__ ql_g,
    const u16* __restrict__ kh_g, const u16* __restrict__ kl_g,
    const u16* __restrict__ vt_g, float* __restrict__ out) {
  __shared__ __align__(16) char lds[106496];
  // buf layout (48KB): kh[16K] | kl[16K] | v[16K]; two bufs; p_lds at 96K
  char* p_lds = lds + 98304;   // 8 waves x 1KB

  const int tid = threadIdx.x;
  const int l = tid & 63, w = tid >> 6;
  const int l15 = l & 15, l4 = l >> 4;
  int wg = blockIdx.x;
  int b  = (wg & 7) * 8 + (wg >> 6);
  int qt = (wg >> 3) & 7;
  const int kbyte = l4 * 16;

  // ---- Q fragments (16 rows/wave, hi/lo) ----
  const int q0 = qt * 128 + w * 16;
  const size_t qtok = (size_t)(b * 1024 + q0 + l15);
  const u16* qhp = qh_g + (qtok << 8) + l4 * 8;
  const u16* qlp = ql_g + (qtok << 8) + l4 * 8;
  bf16x8 qfh[8], qfl[8];
  #pragma unroll
  for (int kk = 0; kk < 8; kk++) {
    qfh[kk] = *(const bf16x8*)(qhp + kk * 32);
    qfl[kk] = *(const bf16x8*)(qlp + kk * 32);
  }

  f32x4 O[16];
  #pragma unroll
  for (int i = 0; i < 16; i++) O[i] = (f32x4){0.f, 0.f, 0.f, 0.f};
  float mrow[4] = {-1e30f, -1e30f, -1e30f, -1e30f};
  float lrow[4] = {0.f, 0.f, 0.f, 0.f};

  const char* khb = (const char*)(kh_g + ((size_t)b << 18));
  const char* klb = (const char*)(kl_g + ((size_t)b << 18));
  const char* vtb = (const char*)(vt_g + ((size_t)b << 18));
  char* pw = p_lds + w * 1024;

  // stage tile 0 into buf 0
  {
    #pragma unroll
    for (int i = 0; i < 2; i++) {
      int co = i * 8192 + w * 1024;
      gl_lds16(khb + co + l * 16, lds + co);
      gl_lds16(klb + co + l * 16, lds + 16384 + co);
      gl_lds16(vtb + co + l * 16, lds + 32768 + co);
    }
  }
  __syncthreads();

  for (int t0 = 0; t0 < 1024; t0 += 32) {
    char* cbuf = lds + ((t0 >> 5) & 1) * 49152;
    // ---- prefetch next tile into the other buffer ----
    if (t0 + 32 < 1024) {
      char* nbuf = lds + (((t0 >> 5) + 1) & 1) * 49152;
      const char* ks = khb + (t0 + 32) * 512;
      const char* ls = klb + (t0 + 32) * 512;
      const char* vs = vtb + ((t0 + 32) >> 5) * 16384;
      #pragma unroll
      for (int i = 0; i < 2; i++) {
        int co = i * 8192 + w * 1024;
        gl_lds16(ks + co + l * 16, nbuf + co);
        gl_lds16(ls + co + l * 16, nbuf + 16384 + co);
        gl_lds16(vs + co + l * 16, nbuf + 32768 + co);
      }
    }
    char* kh_lds = cbuf;
    char* kl_lds = cbuf + 16384;
    char* vt_lds = cbuf + 32768;

    // ---- scores: S[16q][32t], 3-term split ----
    f32x4 sa = (f32x4){0.f, 0.f, 0.f, 0.f};
    f32x4 sb = (f32x4){0.f, 0.f, 0.f, 0.f};
    #pragma unroll
    for (int kk = 0; kk < 8; kk++) {
      int slot = (kk << 2) + l4;
      int r0 = l15, r1 = l15 + 16;
      int o0 = (r0 << 9) + (((slot + 2 * r0) & 31) << 4);
      int o1 = (r1 << 9) + (((slot + 2 * r1) & 31) << 4);
      bf16x8 bh0 = *(const bf16x8*)(kh_lds + o0);
      bf16x8 bl0 = *(const bf16x8*)(kl_lds + o0);
      bf16x8 bh1 = *(const bf16x8*)(kh_lds + o1);
      bf16x8 bl1 = *(const bf16x8*)(kl_lds + o1);
      sa = mfma16(qfh[kk], bh0, sa);
      sa = mfma16(qfl[kk], bh0, sa);
      sa = mfma16(qfh[kk], bl0, sa);
      sb = mfma16(qfh[kk], bh1, sb);
      sb = mfma16(qfl[kk], bh1, sb);
      sb = mfma16(qfh[kk], bl1, sb);
    }

    // ---- online softmax with defer-max (THR=8) ----
    float p0[4], p1[4];
    {
      bool need = false;
      float lmax[4];
      #pragma unroll
      for (int j = 0; j < 4; j++) {
        lmax[j] = fmaxf(sa[j], sb[j]);
        need = need || (lmax[j] > mrow[j] + 8.f);
      }
      if (__any(need)) {
        float scv[4];
        #pragma unroll
        for (int j = 0; j < 4; j++) {
          float mx = lmax[j];
          mx = fmaxf(mx, __shfl_xor(mx, 1));
          mx = fmaxf(mx, __shfl_xor(mx, 2));
          mx = fmaxf(mx, __shfl_xor(mx, 4));
          mx = fmaxf(mx, __shfl_xor(mx, 8));
          float mn = fmaxf(mrow[j], mx);
          scv[j] = __expf(mrow[j] - mn);
          mrow[j] = mn;
          lrow[j] *= scv[j];
        }
        #pragma unroll
        for (int i = 0; i < 16; i++) {
          O[i][0] *= scv[0]; O[i][1] *= scv[1];
          O[i][2] *= scv[2]; O[i][3] *= scv[3];
        }
      }
      #pragma unroll
      for (int j = 0; j < 4; j++) {
        p0[j] = __expf(sa[j] - mrow[j]);
        p1[j] = __expf(sb[j] - mrow[j]);
        float rs = p0[j] + p1[j];
        rs += __shfl_xor(rs, 1);
        rs += __shfl_xor(rs, 2);
        rs += __shfl_xor(rs, 4);
        rs += __shfl_xor(rs, 8);
        lrow[j] += rs;
      }
    }

    // ---- P -> per-wave LDS (bf16), re-fragment for PV ----
    #pragma unroll
    for (int j = 0; j < 4; j++) {
      int row = l4 * 4 + j;
      int base = row << 6;
      int sw = (row & 7) << 4;
      *(u16*)(pw + ((base + l15 * 2) ^ sw)) = f2bf(p0[j]);
      *(u16*)(pw + ((base + (l15 + 16) * 2) ^ sw)) = f2bf(p1[j]);
    }
    asm volatile("s_waitcnt lgkmcnt(0)" ::: "memory");
    __builtin_amdgcn_sched_barrier(0);
    bf16x8 pa = *(const bf16x8*)(pw + (((l15 << 6) + kbyte) ^ ((l15 & 7) << 4)));

    // ---- PV: O += P * V ----
    #pragma unroll
    for (int dt = 0; dt < 16; dt++) {
      int d = dt * 16 + l15;
      bf16x8 vb = *(const bf16x8*)(vt_lds + (((d << 6) + kbyte) ^ ((d & 7) << 4)));
      O[dt] = mfma16(pa, vb, O[dt]);
    }

    __syncthreads();   // drains prefetch (vmcnt 0) + all waves done with cbuf
  }

  // ---- epilogue ----
  float inv[4];
  #pragma unroll
  for (int j = 0; j < 4; j++) inv[j] = 1.0f / lrow[j];
  #pragma unroll
  for (int dt = 0; dt < 16; dt++) {
    #pragma unroll
    for (int j = 0; j < 4; j++) {
      size_t orow = (size_t)(b * 1024 + q0 + l4 * 4 + j);
      out[(orow << 8) + dt * 16 + l15] = O[dt][j] * inv[j];
    }
  }
}

// ============================================================
extern "C" void kernel_launch(void* const* d_in, const int* in_sizes, int n_in,
                              void* d_out, int out_size, void* d_ws, size_t ws_size,
                              hipStream_t stream) {
  (void)in_sizes; (void)n_in; (void)out_size; (void)ws_size;
  const float* x  = (const float*)d_in[0];
  const float* Wq = (const float*)d_in[1];
  const float* bq = (const float*)d_in[2];
  const float* Wk = (const float*)d_in[3];
  const float* bk = (const float*)d_in[4];
  const float* Wv = (const float*)d_in[5];
  const float* bv = (const float*)d_in[6];
  float* out = (float*)d_out;
  char* ws = (char*)d_ws;

  u16* qh  = (u16*)(ws);
  u16* ql  = (u16*)(ws + 33554432);
  u16* kh  = (u16*)(ws + 67108864);
  u16* kl  = (u16*)(ws + 100663296);
  u16* vt  = (u16*)(ws + 134217728);
  u16* wsp = (u16*)(ws + 167772160);   // 768KB swizzled weights

  prep_w_kernel<<<dim3(768), dim3(256), 0, stream>>>(Wq, Wk, Wv, wsp);
  proj_kernel<<<dim3(256), dim3(512), 0, stream>>>(
      x, bq, bk, bv, wsp, qh, ql, kh, kl, vt);
  attn_kernel<<<dim3(512), dim3(512), 0, stream>>>(qh, ql, kh, kl, vt, out);
}